// Round 4
// baseline (158.903 us; speedup 1.0000x reference)
//
#include <hip/hip_runtime.h>
#include <float.h>

#define Bb 2
#define Ll 256
#define Ss 384
#define Hh 768
#define Tc 16
#define Dc 50
#define WD 100
#define CV 128
#define NG 200     // 4*Dc gates
#define OUTC 968   // H + WD + 2*Dc
#define NW 6       // 384/64 s-words per row

// ws layout:
//   float [0, 256)         minv partials
//   float [256, 51456)     xproj table [2][128][200], bias folded in
//   u64   [51456f..]       packed pieces2word bitmask [B*L][6]

__device__ inline float tanh_fast(float x) {
    float e = __expf(2.f * x);
    return 1.f - 2.f / (e + 1.f);
}
__device__ inline float sigmoid_fast(float x) {
    return 1.f / (1.f + __expf(-x));
}

// ---------------- prep: min partials | xproj | word-embed gather | mask pack ----------------
// grid 348: [0,256) min, [256,272) xproj, [272,336) gather, [336,348) pack

__global__ __launch_bounds__(256) void prep_kernel(
        const float* __restrict__ bert, const float* __restrict__ char_table,
        const float* __restrict__ Wih_f, const float* __restrict__ bih_f, const float* __restrict__ bhh_f,
        const float* __restrict__ Wih_b, const float* __restrict__ bih_b, const float* __restrict__ bhh_b,
        const int* __restrict__ word_ids, const float* __restrict__ word_table,
        const int* __restrict__ p2w,
        float* __restrict__ minp, float* __restrict__ xpt,
        unsigned long long* __restrict__ pmask, float* __restrict__ out) {
    int blk = blockIdx.x, tid = threadIdx.x;
    if (blk < 256) {
        const int n = Bb * Ss * Hh;
        float m = FLT_MAX;
        for (int i = blk * 256 + tid; i < n; i += 256 * 256) m = fminf(m, bert[i]);
        #pragma unroll
        for (int off = 32; off; off >>= 1) m = fminf(m, __shfl_down(m, off, 64));
        __shared__ float red[4];
        if ((tid & 63) == 0) red[tid >> 6] = m;
        __syncthreads();
        if (tid == 0) minp[blk] = fminf(fminf(red[0], red[1]), fminf(red[2], red[3]));
    } else if (blk < 272) {
        int idx = blk - 256;            // dir*8 + cid-chunk
        int dir = idx >> 3, c0 = (idx & 7) * 16;
        const float* Wih = dir ? Wih_b : Wih_f;
        const float* bih = dir ? bih_b : bih_f;
        const float* bhh = dir ? bhh_b : bhh_f;
        __shared__ float ct[16][Dc];
        for (int e = tid; e < 16 * Dc; e += 256)
            ((float*)ct)[e] = char_table[c0 * Dc + e];
        __syncthreads();
        if (tid < NG) {
            float w[Dc];
            #pragma unroll
            for (int j = 0; j < Dc; j++) w[j] = Wih[tid * Dc + j];
            float bias = bih[tid] + bhh[tid];
            for (int cid = 0; cid < 16; cid++) {
                float a = bias;
                #pragma unroll
                for (int j = 0; j < Dc; j++) a += w[j] * ct[cid][j];
                xpt[(dir * CV + c0 + cid) * NG + tid] = a;
            }
        }
    } else if (blk < 336) {
        for (int i = (blk - 272) * 256 + tid; i < Bb * Ll * WD; i += 64 * 256) {
            int bl = i / WD, d = i - bl * WD;
            out[(size_t)bl * OUTC + Hh + d] = word_table[(size_t)word_ids[bl] * WD + d];
        }
    } else {
        // pack p2w -> bitmask, one 64-int word per wave-iteration via ballot
        int gw   = (blk - 336) * 4 + (tid >> 6);   // 0..47
        int lane = tid & 63;
        for (int k = 0; k < 64; k++) {             // 48 waves * 64 = 3072 words
            int W = gw * 64 + k;                   // word idx: bl*6 + wi
            int v = p2w[(size_t)W * 64 + lane];    // == p2w[bl*384 + wi*64 + lane]
            unsigned long long bm = __ballot(v != 0);
            if (lane == 0) pmask[W] = bm;
        }
    }
}

// ---------------- word_reps masked max, bitmask edition ----------------
// grid 384 = 6 h-chunks(128) * 32 l-tiles(8) * 2 b; 384 threads: wave w owns s-word w

#define LT 8

__global__ __launch_bounds__(384) void word_kernel(
        const float* __restrict__ bert, const unsigned long long* __restrict__ pmask,
        const float* __restrict__ minp, float* __restrict__ out) {
    int tid = threadIdx.x;
    __shared__ float sminv;
    __shared__ float sacc[NW][LT][128];
    if (tid < 64) {
        float m = fminf(fminf(minp[tid], minp[tid + 64]),
                        fminf(minp[tid + 128], minp[tid + 192]));
        #pragma unroll
        for (int off = 32; off; off >>= 1) m = fminf(m, __shfl_down(m, off, 64));
        if (tid == 0) sminv = m;
    }
    int blk = blockIdx.x;
    int hc = blk % 6;            // h-chunk of 128
    int lt = (blk / 6) & 31;     // l-tile of 8
    int b  = blk / 192;
    int l0 = lt * LT;
    int w    = tid >> 6;         // wave -> s-word (0..5)
    int lane = tid & 63;

    // row masks for this wave's word, forced to SGPRs
    unsigned mlo[LT], mhi[LT];
    #pragma unroll
    for (int r = 0; r < LT; r++) {
        unsigned long long mw = pmask[(size_t)(b * Ll + l0 + r) * NW + w];
        mlo[r] = __builtin_amdgcn_readfirstlane((unsigned)mw);
        mhi[r] = __builtin_amdgcn_readfirstlane((unsigned)(mw >> 32));
    }

    const float2* bb2 = (const float2*)(bert + (size_t)b * Ss * Hh) + hc * 64 + lane;

    float2 acc[LT];
    #pragma unroll
    for (int r = 0; r < LT; r++) { acc[r].x = -FLT_MAX; acc[r].y = -FLT_MAX; }

    int sbase = w * 64;
    #pragma unroll 8
    for (int j = 0; j < 64; j++) {
        float2 v = bb2[(size_t)(sbase + j) * 384];
        #pragma unroll
        for (int r = 0; r < LT; r++) {
            unsigned bit = (j < 32) ? (mlo[r] & (1u << j)) : (mhi[r] & (1u << (j - 32)));
            if (bit) {               // scalar condition -> uniform branch
                acc[r].x = fmaxf(acc[r].x, v.x);
                acc[r].y = fmaxf(acc[r].y, v.y);
            }
        }
    }
    #pragma unroll
    for (int r = 0; r < LT; r++)
        *(float2*)&sacc[w][r][lane * 2] = acc[r];
    __syncthreads();

    float mv = sminv;
    for (int e = tid; e < LT * 128; e += 384) {
        int r = e >> 7, c = e & 127;
        float m0 = fmaxf(sacc[0][r][c], sacc[1][r][c]);
        float m1 = fmaxf(sacc[2][r][c], sacc[3][r][c]);
        float m2 = fmaxf(sacc[4][r][c], sacc[5][r][c]);
        float m  = fmaxf(fmaxf(m0, m1), m2);
        if (m == -FLT_MAX) m = mv;      // fully-masked row -> global min fill
        out[((size_t)(b * Ll + l0 + r)) * OUTC + hc * 128 + c] = m;
    }
}

// ---------------- char bi-LSTM: one block per (chain, dir), xproj from table ----------------

__global__ __launch_bounds__(256) void lstm_kernel(
        const int* __restrict__ char_ids, const int* __restrict__ char_count,
        const float* __restrict__ Whh_f, const float* __restrict__ Whh_b,
        const float* __restrict__ xpt, float* __restrict__ out) {
    int n = blockIdx.x, dir = blockIdx.y, tid = threadIdx.x;
    const float* Whh = dir ? Whh_b : Whh_f;

    __shared__ float xg[Tc][NG];
    __shared__ float gs[NG];
    __shared__ __align__(16) float hs[52];
    __shared__ int scid[Tc];

    int len = char_count[n];
    if (len < 1) len = 1;
    if (tid < Tc) {
        int t = tid;
        int st = dir ? (t < len ? len - 1 - t : t) : t;   // bwd: reverse valid prefix
        scid[t] = char_ids[n * Tc + st];
    }
    if (tid < 52) hs[tid] = 0.f;
    __syncthreads();

    for (int e = tid; e < Tc * NG; e += 256) {
        int t = e / NG, g = e - t * NG;
        xg[t][g] = xpt[(dir * CV + scid[t]) * NG + g];    // coalesced row gather
    }
    float w[52];
    if (tid < NG) {
        #pragma unroll
        for (int j = 0; j < Dc; j++) w[j] = Whh[tid * Dc + j];
        w[50] = 0.f; w[51] = 0.f;
    }
    __syncthreads();

    float c = 0.f, maxv = -FLT_MAX;
    for (int t = 0; t < Tc; t++) {
        if (tid < NG) {
            float g = xg[t][tid];
            #pragma unroll
            for (int j = 0; j < 52; j += 4) {
                float4 hv = *(const float4*)&hs[j];      // broadcast reads
                g += hv.x * w[j] + hv.y * w[j+1] + hv.z * w[j+2] + hv.w * w[j+3];
            }
            gs[tid] = g;
        }
        __syncthreads();
        if (tid < Dc) {
            float si = sigmoid_fast(gs[tid]);
            float sf = sigmoid_fast(gs[tid + 50]);
            float tg = tanh_fast(gs[tid + 100]);
            float so = sigmoid_fast(gs[tid + 150]);
            c = sf * c + si * tg;
            float h = so * tanh_fast(c);
            hs[tid] = h;
            if (t < len) maxv = fmaxf(maxv, h);          // ragged max (scan order == valid region both dirs)
        }
        __syncthreads();
    }
    if (tid < Dc)
        out[(size_t)n * OUTC + (Hh + WD) + dir * Dc + tid] = maxv;
}

extern "C" void kernel_launch(void* const* d_in, const int* in_sizes, int n_in,
                              void* d_out, int out_size, void* d_ws, size_t ws_size,
                              hipStream_t stream) {
    const float* bert       = (const float*)d_in[0];
    const int*   p2w        = (const int*)d_in[1];
    const int*   word_ids   = (const int*)d_in[2];
    const int*   char_count = (const int*)d_in[3];
    const int*   char_ids   = (const int*)d_in[4];
    // d_in[5] token_masks_char: consistent with char_count, unused
    const float* word_table = (const float*)d_in[6];
    const float* char_table = (const float*)d_in[7];
    const float* Wih_f = (const float*)d_in[8];
    const float* Whh_f = (const float*)d_in[9];
    const float* bih_f = (const float*)d_in[10];
    const float* bhh_f = (const float*)d_in[11];
    const float* Wih_b = (const float*)d_in[12];
    const float* Whh_b = (const float*)d_in[13];
    const float* bih_b = (const float*)d_in[14];
    const float* bhh_b = (const float*)d_in[15];
    float* out = (float*)d_out;

    float* minp = (float*)d_ws;                      // 256 floats
    float* xpt  = minp + 256;                        // 2*128*200 floats
    unsigned long long* pmask = (unsigned long long*)(xpt + 2 * CV * NG);  // 512*6 u64

    prep_kernel<<<348, 256, 0, stream>>>(
        bert, char_table, Wih_f, bih_f, bhh_f, Wih_b, bih_b, bhh_b,
        word_ids, word_table, p2w, minp, xpt, pmask, out);
    word_kernel<<<384, 384, 0, stream>>>(bert, pmask, minp, out);
    lstm_kernel<<<dim3(512, 2), 256, 0, stream>>>(
        char_ids, char_count, Whh_f, Whh_b, xpt, out);
}

// Round 5
// 130.103 us; speedup vs baseline: 1.2214x; 1.2214x over previous
//
#include <hip/hip_runtime.h>
#include <float.h>

#define Bb 2
#define Ll 256
#define Ss 384
#define Hh 768
#define Tc 16
#define Dc 50
#define WD 100
#define CV 128
#define NG 200     // 4*Dc gates
#define OUTC 968   // H + WD + 2*Dc
#define LT 8       // l rows per word block
#define NSC 4      // s chunks

// ws layout (floats):
//   [0, 256)      minv partials
//   [256, 51456)  xproj table [2][128][200], bias folded in
//   [51456, ...)  word partials [NSC][B*L][Hh]  (6.3 MB)

__device__ inline float tanh_fast(float x) {
    float e = __expf(2.f * x);
    return 1.f - 2.f / (e + 1.f);
}
__device__ inline float sigmoid_fast(float x) {
    return 1.f / (1.f + __expf(-x));
}

// ================= kernel A: min | xproj | embed | word partials =================
// grid 1872: [0,256) min, [256,272) xproj, [272,336) embed, [336,1872) word

__global__ __launch_bounds__(256) void kernelA(
        const float* __restrict__ bert, const int* __restrict__ p2w,
        const float* __restrict__ char_table,
        const float* __restrict__ Wih_f, const float* __restrict__ bih_f, const float* __restrict__ bhh_f,
        const float* __restrict__ Wih_b, const float* __restrict__ bih_b, const float* __restrict__ bhh_b,
        const int* __restrict__ word_ids, const float* __restrict__ word_table,
        float* __restrict__ minp, float* __restrict__ xpt, float* __restrict__ partial,
        float* __restrict__ out) {
    int blk = blockIdx.x, tid = threadIdx.x;
    if (blk < 256) {
        const int n = Bb * Ss * Hh;
        float m = FLT_MAX;
        for (int i = blk * 256 + tid; i < n; i += 256 * 256) m = fminf(m, bert[i]);
        #pragma unroll
        for (int off = 32; off; off >>= 1) m = fminf(m, __shfl_down(m, off, 64));
        __shared__ float red[4];
        if ((tid & 63) == 0) red[tid >> 6] = m;
        __syncthreads();
        if (tid == 0) minp[blk] = fminf(fminf(red[0], red[1]), fminf(red[2], red[3]));
    } else if (blk < 272) {
        int idx = blk - 256;            // dir*8 + cid-chunk
        int dir = idx >> 3, c0 = (idx & 7) * 16;
        const float* Wih = dir ? Wih_b : Wih_f;
        const float* bih = dir ? bih_b : bih_f;
        const float* bhh = dir ? bhh_b : bhh_f;
        __shared__ float ct[16][Dc];
        for (int e = tid; e < 16 * Dc; e += 256)
            ((float*)ct)[e] = char_table[c0 * Dc + e];
        __syncthreads();
        if (tid < NG) {
            float w[Dc];
            #pragma unroll
            for (int j = 0; j < Dc; j++) w[j] = Wih[tid * Dc + j];
            float bias = bih[tid] + bhh[tid];
            for (int cid = 0; cid < 16; cid++) {
                float a = bias;
                #pragma unroll
                for (int j = 0; j < Dc; j++) a += w[j] * ct[cid][j];
                xpt[(dir * CV + c0 + cid) * NG + tid] = a;
            }
        }
    } else if (blk < 336) {
        for (int i = (blk - 272) * 256 + tid; i < Bb * Ll * WD; i += 64 * 256) {
            int bl = i / WD, d = i - bl * WD;
            out[(size_t)bl * OUTC + Hh + d] = word_table[(size_t)word_ids[bl] * WD + d];
        }
    } else {
        // ---- word partial: block = (b, sc, lt, hc); wave owns 24 s ----
        int idx = blk - 336;           // 0..1535
        int hc  = idx % 6;             // h-chunk of 128
        int lt  = (idx / 6) & 31;      // l-tile of 8
        int bsc = idx / 192;           // b*4 + sc
        int b   = bsc >> 2, sc = bsc & 3;
        int w    = tid >> 6;           // wave -> 24-s slice
        int lane = tid & 63;
        int s0 = sc * 96 + w * 24;

        // per-row 24-bit masks via ballot -> SGPRs (no mask traffic in the loop)
        const int* pm = p2w + ((size_t)(b * Ll + lt * LT)) * Ss + s0;
        unsigned m[LT];
        #pragma unroll
        for (int r = 0; r < LT; r++) {
            int v = (lane < 24) ? pm[r * Ss + lane] : 0;
            unsigned long long bal = __ballot(v != 0);
            m[r] = __builtin_amdgcn_readfirstlane((unsigned)bal);
        }

        const float2* bb2 = (const float2*)(bert + (size_t)b * Ss * Hh) + hc * 64 + lane;
        float2 acc[LT];
        #pragma unroll
        for (int r = 0; r < LT; r++) { acc[r].x = -FLT_MAX; acc[r].y = -FLT_MAX; }

        #pragma unroll
        for (int j = 0; j < 24; j++) {
            float2 v = bb2[(size_t)(s0 + j) * 384];
            #pragma unroll
            for (int r = 0; r < LT; r++) {
                if (m[r] & (1u << j)) {          // scalar (wave-uniform) branch
                    acc[r].x = fmaxf(acc[r].x, v.x);
                    acc[r].y = fmaxf(acc[r].y, v.y);
                }
            }
        }

        __shared__ float sacc[4][LT][128];
        #pragma unroll
        for (int r = 0; r < LT; r++)
            *(float2*)&sacc[w][r][lane * 2] = acc[r];
        __syncthreads();

        for (int e = tid; e < LT * 128; e += 256) {
            int r = e >> 7, c = e & 127;
            float m0 = fmaxf(fmaxf(sacc[0][r][c], sacc[1][r][c]),
                             fmaxf(sacc[2][r][c], sacc[3][r][c]));
            size_t row = (size_t)b * Ll + lt * LT + r;
            partial[((size_t)sc * (Bb * Ll) + row) * Hh + hc * 128 + c] = m0;
        }
    }
}

// ================= kernel B: LSTM | word finalize =================
// grid 1408: [0,1024) lstm (n=blk>>1, dir=blk&1), [1024,1408) finalize

__global__ __launch_bounds__(256) void kernelB(
        const int* __restrict__ char_ids, const int* __restrict__ char_count,
        const float* __restrict__ Whh_f, const float* __restrict__ Whh_b,
        const float* __restrict__ xpt, const float* __restrict__ partial,
        const float* __restrict__ minp, float* __restrict__ out) {
    int blk = blockIdx.x, tid = threadIdx.x;
    if (blk < 1024) {
        int n = blk >> 1, dir = blk & 1;
        const float* Whh = dir ? Whh_b : Whh_f;

        __shared__ float xg[Tc][NG];
        __shared__ float gs[NG];
        __shared__ __align__(16) float hs[52];
        __shared__ int scid[Tc];

        int len = char_count[n];
        if (len < 1) len = 1;
        if (tid < Tc) {
            int t = tid;
            int st = dir ? (t < len ? len - 1 - t : t) : t;   // bwd: reverse valid prefix
            scid[t] = char_ids[n * Tc + st];
        }
        if (tid < 52) hs[tid] = 0.f;
        __syncthreads();

        for (int e = tid; e < Tc * NG; e += 256) {
            int t = e / NG, g = e - t * NG;
            xg[t][g] = xpt[(dir * CV + scid[t]) * NG + g];
        }
        float w[52];
        if (tid < NG) {
            #pragma unroll
            for (int j = 0; j < Dc; j++) w[j] = Whh[tid * Dc + j];
            w[50] = 0.f; w[51] = 0.f;
        }
        __syncthreads();

        float c = 0.f, maxv = -FLT_MAX;
        for (int t = 0; t < Tc; t++) {
            if (tid < NG) {
                float g = xg[t][tid];
                #pragma unroll
                for (int j = 0; j < 52; j += 4) {
                    float4 hv = *(const float4*)&hs[j];
                    g += hv.x * w[j] + hv.y * w[j+1] + hv.z * w[j+2] + hv.w * w[j+3];
                }
                gs[tid] = g;
            }
            __syncthreads();
            if (tid < Dc) {
                float si = sigmoid_fast(gs[tid]);
                float sf = sigmoid_fast(gs[tid + 50]);
                float tg = tanh_fast(gs[tid + 100]);
                float so = sigmoid_fast(gs[tid + 150]);
                c = sf * c + si * tg;
                float h = so * tanh_fast(c);
                hs[tid] = h;
                if (t < len) maxv = fmaxf(maxv, h);   // ragged max
            }
            __syncthreads();
        }
        if (tid < Dc)
            out[(size_t)n * OUTC + (Hh + WD) + dir * Dc + tid] = maxv;
    } else {
        // ---- finalize word_reps: reduce 4 s-chunk partials + minv fill ----
        __shared__ float sminv;
        if (tid < 64) {
            float m = fminf(fminf(minp[tid], minp[tid + 64]),
                            fminf(minp[tid + 128], minp[tid + 192]));
            #pragma unroll
            for (int off = 32; off; off >>= 1) m = fminf(m, __shfl_down(m, off, 64));
            if (tid == 0) sminv = m;
        }
        __syncthreads();
        float mv = sminv;
        const int TOT = Bb * Ll * Hh;        // 393216
        for (int e = (blk - 1024) * 256 + tid; e < TOT; e += 384 * 256) {
            float m = fmaxf(fmaxf(partial[e], partial[TOT + e]),
                            fmaxf(partial[2 * TOT + e], partial[3 * TOT + e]));
            if (m == -FLT_MAX) m = mv;       // fully-masked row
            int row = e / Hh, c = e - row * Hh;
            out[(size_t)row * OUTC + c] = m;
        }
    }
}

extern "C" void kernel_launch(void* const* d_in, const int* in_sizes, int n_in,
                              void* d_out, int out_size, void* d_ws, size_t ws_size,
                              hipStream_t stream) {
    const float* bert       = (const float*)d_in[0];
    const int*   p2w        = (const int*)d_in[1];
    const int*   word_ids   = (const int*)d_in[2];
    const int*   char_count = (const int*)d_in[3];
    const int*   char_ids   = (const int*)d_in[4];
    // d_in[5] token_masks_char: consistent with char_count, unused
    const float* word_table = (const float*)d_in[6];
    const float* char_table = (const float*)d_in[7];
    const float* Wih_f = (const float*)d_in[8];
    const float* Whh_f = (const float*)d_in[9];
    const float* bih_f = (const float*)d_in[10];
    const float* bhh_f = (const float*)d_in[11];
    const float* Wih_b = (const float*)d_in[12];
    const float* Whh_b = (const float*)d_in[13];
    const float* bih_b = (const float*)d_in[14];
    const float* bhh_b = (const float*)d_in[15];
    float* out = (float*)d_out;

    float* minp    = (float*)d_ws;               // 256
    float* xpt     = minp + 256;                 // 2*128*200
    float* partial = xpt + 2 * CV * NG;          // 4*512*768

    kernelA<<<1872, 256, 0, stream>>>(
        bert, p2w, char_table, Wih_f, bih_f, bhh_f, Wih_b, bih_b, bhh_b,
        word_ids, word_table, minp, xpt, partial, out);
    kernelB<<<1408, 256, 0, stream>>>(
        char_ids, char_count, Whh_f, Whh_b, xpt, partial, minp, out);
}

// Round 6
// 123.429 us; speedup vs baseline: 1.2874x; 1.0541x over previous
//
#include <hip/hip_runtime.h>
#include <float.h>

#define Bb 2
#define Ll 256
#define Ss 384
#define Hh 768
#define Tc 16
#define Dc 50
#define WD 100
#define CV 128
#define NG 200     // 4*Dc gates
#define OUTC 968   // H + WD + 2*Dc

// ws layout (floats):
//   [0, 128)      minv partials
//   [128, ...)    xproj table [2][128][200], bias folded in

__device__ inline float tanh_fast(float x) {
    float e = __expf(2.f * x);
    return 1.f - 2.f / (e + 1.f);
}
__device__ inline float sigmoid_fast(float x) {
    return 1.f / (1.f + __expf(-x));
}

// ================= kernel 1: min partials | xproj | word-embed =================
// grid 208: [0,128) min, [128,144) xproj, [144,208) embed

__global__ __launch_bounds__(256) void kernel1(
        const float* __restrict__ bert, const float* __restrict__ char_table,
        const float* __restrict__ Wih_f, const float* __restrict__ bih_f, const float* __restrict__ bhh_f,
        const float* __restrict__ Wih_b, const float* __restrict__ bih_b, const float* __restrict__ bhh_b,
        const int* __restrict__ word_ids, const float* __restrict__ word_table,
        float* __restrict__ minp, float* __restrict__ xpt, float* __restrict__ out) {
    int blk = blockIdx.x, tid = threadIdx.x;
    if (blk < 128) {
        const int n4 = (Bb * Ss * Hh) / 4;       // 147456 float4
        const float4* b4 = (const float4*)bert;
        float m = FLT_MAX;
        for (int i = blk * 256 + tid; i < n4; i += 128 * 256) {
            float4 v = b4[i];
            m = fminf(m, fminf(fminf(v.x, v.y), fminf(v.z, v.w)));
        }
        #pragma unroll
        for (int off = 32; off; off >>= 1) m = fminf(m, __shfl_down(m, off, 64));
        __shared__ float red[4];
        if ((tid & 63) == 0) red[tid >> 6] = m;
        __syncthreads();
        if (tid == 0) minp[blk] = fminf(fminf(red[0], red[1]), fminf(red[2], red[3]));
    } else if (blk < 144) {
        int idx = blk - 128;            // dir*8 + cid-chunk
        int dir = idx >> 3, c0 = (idx & 7) * 16;
        const float* Wih = dir ? Wih_b : Wih_f;
        const float* bih = dir ? bih_b : bih_f;
        const float* bhh = dir ? bhh_b : bhh_f;
        __shared__ float ct[16][Dc];
        for (int e = tid; e < 16 * Dc; e += 256)
            ((float*)ct)[e] = char_table[c0 * Dc + e];
        __syncthreads();
        if (tid < NG) {
            float w[Dc];
            #pragma unroll
            for (int j = 0; j < Dc; j++) w[j] = Wih[tid * Dc + j];
            float bias = bih[tid] + bhh[tid];
            for (int cid = 0; cid < 16; cid++) {
                float a = bias;
                #pragma unroll
                for (int j = 0; j < Dc; j++) a += w[j] * ct[cid][j];
                xpt[(dir * CV + c0 + cid) * NG + tid] = a;
            }
        }
    } else {
        for (int i = (blk - 144) * 256 + tid; i < Bb * Ll * WD; i += 64 * 256) {
            int bl = i / WD, d = i - bl * WD;
            out[(size_t)bl * OUTC + Hh + d] = word_table[(size_t)word_ids[bl] * WD + d];
        }
    }
}

// ================= kernel 2: LSTM | word_reps direct =================
// grid 1792: [0,1024) lstm (n=blk>>1, dir=blk&1), [1024,1792) word
// word block = (b, l-tile of 4, h-chunk of 128); wave owns 96 s

__global__ __launch_bounds__(256) void kernel2(
        const int* __restrict__ char_ids, const int* __restrict__ char_count,
        const float* __restrict__ Whh_f, const float* __restrict__ Whh_b,
        const float* __restrict__ xpt,
        const float* __restrict__ bert, const int* __restrict__ p2w,
        const float* __restrict__ minp, float* __restrict__ out) {
    __shared__ __align__(16) char smem[13888];
    int blk = blockIdx.x, tid = threadIdx.x;

    if (blk < 1024) {
        // ---------------- char bi-LSTM ----------------
        float (*xg)[NG] = (float (*)[NG])smem;            // 16*200*4 = 12800
        float* gs  = (float*)(smem + 12800);              // 800
        float* hs  = (float*)(smem + 13600);              // 208 (52 floats)
        int*   scid = (int*)(smem + 13808);               // 64

        int n = blk >> 1, dir = blk & 1;
        const float* Whh = dir ? Whh_b : Whh_f;

        int len = char_count[n];
        if (len < 1) len = 1;
        if (tid < Tc) {
            int t = tid;
            int st = dir ? (t < len ? len - 1 - t : t) : t;   // bwd: reverse valid prefix
            scid[t] = char_ids[n * Tc + st];
        }
        if (tid < 52) hs[tid] = 0.f;
        __syncthreads();

        // stage xproj rows as float4 (row stride 200 floats = 800B, 16B aligned)
        for (int e = tid; e < Tc * (NG / 4); e += 256) {
            int t = e / 50, q = e - t * 50;
            ((float4*)xg[t])[q] = ((const float4*)&xpt[(dir * CV + scid[t]) * NG])[q];
        }
        float w[52];
        if (tid < NG) {
            #pragma unroll
            for (int j = 0; j < Dc; j++) w[j] = Whh[tid * Dc + j];
            w[50] = 0.f; w[51] = 0.f;
        }
        __syncthreads();

        float c = 0.f, maxv = -FLT_MAX;
        for (int t = 0; t < Tc; t++) {
            if (tid < NG) {
                float g = xg[t][tid];
                #pragma unroll
                for (int j = 0; j < 52; j += 4) {
                    float4 hv = *(const float4*)&hs[j];   // broadcast reads
                    g += hv.x * w[j] + hv.y * w[j+1] + hv.z * w[j+2] + hv.w * w[j+3];
                }
                gs[tid] = g;
            }
            __syncthreads();
            if (tid < Dc) {
                float si = sigmoid_fast(gs[tid]);
                float sf = sigmoid_fast(gs[tid + 50]);
                float tg = tanh_fast(gs[tid + 100]);
                float so = sigmoid_fast(gs[tid + 150]);
                c = sf * c + si * tg;
                float h = so * tanh_fast(c);
                hs[tid] = h;
                if (t < len) maxv = fmaxf(maxv, h);       // ragged max
            }
            __syncthreads();
        }
        if (tid < Dc)
            out[(size_t)n * OUTC + (Hh + WD) + dir * Dc + tid] = maxv;
    } else {
        // ---------------- word_reps masked max, direct write ----------------
        float (*sacc)[4][128] = (float (*)[4][128])smem;  // 4 waves * 4 rows * 128 = 8192
        float* sminv = (float*)(smem + 8192);

        if (tid < 64) {
            float m = fminf(minp[tid], minp[tid + 64]);
            #pragma unroll
            for (int off = 32; off; off >>= 1) m = fminf(m, __shfl_down(m, off, 64));
            if (tid == 0) *sminv = m;
        }
        int idx = blk - 1024;          // 0..767
        int hc  = idx % 6;             // h-chunk of 128
        int lt  = (idx / 6) & 63;      // l-tile of 4
        int b   = idx / 384;
        int l0  = lt * 4;
        int w    = tid >> 6;           // wave -> s range [w*96, w*96+96)
        int lane = tid & 63;
        int s0 = w * 96;

        // 96-bit row masks via 2 ballots -> 3 SGPRs per row
        const int* pm = p2w + ((size_t)(b * Ll + l0)) * Ss + s0;
        unsigned m0[4], m1[4], m2[4];
        #pragma unroll
        for (int r = 0; r < 4; r++) {
            unsigned long long b0 = __ballot(pm[r * Ss + lane] != 0);
            unsigned long long b1 = __ballot(lane < 32 ? (pm[r * Ss + 64 + lane] != 0) : false);
            m0[r] = __builtin_amdgcn_readfirstlane((unsigned)b0);
            m1[r] = __builtin_amdgcn_readfirstlane((unsigned)(b0 >> 32));
            m2[r] = __builtin_amdgcn_readfirstlane((unsigned)b1);
        }

        const float2* bb2 = (const float2*)(bert + (size_t)b * Ss * Hh) + hc * 64 + lane;
        float2 acc[4];
        #pragma unroll
        for (int r = 0; r < 4; r++) { acc[r].x = -FLT_MAX; acc[r].y = -FLT_MAX; }

        for (int jo = 0; jo < 96; jo += 8) {       // 12 groups of 8 loads in flight
            float2 v[8];
            #pragma unroll
            for (int k = 0; k < 8; k++) v[k] = bb2[(size_t)(s0 + jo + k) * 384];
            #pragma unroll
            for (int k = 0; k < 8; k++) {
                int j = jo + k;
                #pragma unroll
                for (int r = 0; r < 4; r++) {
                    unsigned bit = (j < 32 ? m0[r] >> j
                                 : j < 64 ? m1[r] >> (j - 32)
                                          : m2[r] >> (j - 64)) & 1u;
                    if (bit) {                     // wave-uniform scalar branch
                        acc[r].x = fmaxf(acc[r].x, v[k].x);
                        acc[r].y = fmaxf(acc[r].y, v[k].y);
                    }
                }
            }
        }
        #pragma unroll
        for (int r = 0; r < 4; r++)
            *(float2*)&sacc[w][r][lane * 2] = acc[r];
        __syncthreads();

        float mv = *sminv;
        #pragma unroll
        for (int e = tid; e < 4 * 128; e += 256) {
            int r = e >> 7, cx = e & 127;
            float m = fmaxf(fmaxf(sacc[0][r][cx], sacc[1][r][cx]),
                            fmaxf(sacc[2][r][cx], sacc[3][r][cx]));
            if (m == -FLT_MAX) m = mv;             // fully-masked row -> global min fill
            out[((size_t)(b * Ll + l0 + r)) * OUTC + hc * 128 + cx] = m;
        }
    }
}

extern "C" void kernel_launch(void* const* d_in, const int* in_sizes, int n_in,
                              void* d_out, int out_size, void* d_ws, size_t ws_size,
                              hipStream_t stream) {
    const float* bert       = (const float*)d_in[0];
    const int*   p2w        = (const int*)d_in[1];
    const int*   word_ids   = (const int*)d_in[2];
    const int*   char_count = (const int*)d_in[3];
    const int*   char_ids   = (const int*)d_in[4];
    // d_in[5] token_masks_char: consistent with char_count, unused
    const float* word_table = (const float*)d_in[6];
    const float* char_table = (const float*)d_in[7];
    const float* Wih_f = (const float*)d_in[8];
    const float* Whh_f = (const float*)d_in[9];
    const float* bih_f = (const float*)d_in[10];
    const float* bhh_f = (const float*)d_in[11];
    const float* Wih_b = (const float*)d_in[12];
    const float* Whh_b = (const float*)d_in[13];
    const float* bih_b = (const float*)d_in[14];
    const float* bhh_b = (const float*)d_in[15];
    float* out = (float*)d_out;

    float* minp = (float*)d_ws;          // 128 floats
    float* xpt  = minp + 128;            // 2*128*200 floats

    kernel1<<<208, 256, 0, stream>>>(
        bert, char_table, Wih_f, bih_f, bhh_f, Wih_b, bih_b, bhh_b,
        word_ids, word_table, minp, xpt, out);
    kernel2<<<1792, 256, 0, stream>>>(
        char_ids, char_count, Whh_f, Whh_b, xpt, bert, p2w, minp, out);
}